// Round 16
// baseline (64.020 us; speedup 1.0000x reference)
//
#include <hip/hip_runtime.h>
#include <math.h>

// out[b,oc,y,x] = max_t min(p_t, k_t), p = channel-max(32) of x, OOB=-inf.
// x (16,32,256,256) f32, k (32,5,5) f32, out (16,32,256,256) f32.
//
// TWO single-direction streaming passes (round-15 proved conv VALU ~free with
// sorted-tap early exit; fused version convoy-serialized read & write):
//   sort:  rank taps per oc, descending (tiny, exact).
//   A: chanmax x -> xm (d_ws). Pure read stream 134MB (+4MB write). No halo.
//   B: conv from xm halo (L2-resident, ~7MB) with early-exit scan -> out.
//      Pure write stream 131MB (nt-stores).

#define BATCH 16
#define CH    32
#define OCH   32
#define HH    256
#define WW    256
#define HWSZ  (HH * WW)
#define TW    32
#define TH    16
#define LH    20              // TH + 4
#define LW    42              // LDS tile stride (floats)
#define NWGB  (BATCH * (HH / TH) * (WW / TW))   // 2048

typedef float floatx4 __attribute__((ext_vector_type(4)));

// ---- Kernel 0: rank taps (descending k), one block ----
__global__ void sort_taps_kernel(const float* __restrict__ kk, float2* __restrict__ ent) {
    int t = threadIdx.x;
    if (t >= OCH * 25) return;
    int oc = t / 25, i = t % 25;
    float ki = kk[oc * 25 + i];
    int rank = 0;
#pragma unroll
    for (int j = 0; j < 25; ++j) {
        float kj = kk[oc * 25 + j];
        rank += (kj > ki) || (kj == ki && j < i);
    }
    int dy = i / 5, dx = i % 5;
    int off = 4 * (dy * LW + dx);
    ent[oc * 26 + rank] = make_float2(ki, __int_as_float(off));
    if (i == 0) ent[oc * 26 + 25] = make_float2(-INFINITY, __int_as_float(0));
}

// ---- Kernel A: channel max, 16-deep load batches, fully coalesced ----
__global__ __launch_bounds__(256) void chanmax_kernel(const float* __restrict__ x,
                                                      float* __restrict__ xm) {
    int i4 = blockIdx.x * blockDim.x + threadIdx.x;   // 0 .. 262143
    int b  = i4 >> 14;
    int r  = i4 & 16383;
    const float4* base = (const float4*)x + (size_t)b * (CH * (HWSZ / 4)) + r;

    float4 v[16];
#pragma unroll
    for (int j = 0; j < 16; ++j) v[j] = base[(size_t)j * (HWSZ / 4)];
    float4 m = v[0];
#pragma unroll
    for (int j = 1; j < 16; ++j) {
        m.x = fmaxf(m.x, v[j].x); m.y = fmaxf(m.y, v[j].y);
        m.z = fmaxf(m.z, v[j].z); m.w = fmaxf(m.w, v[j].w);
    }
#pragma unroll
    for (int j = 0; j < 16; ++j) v[j] = base[(size_t)(16 + j) * (HWSZ / 4)];
#pragma unroll
    for (int j = 0; j < 16; ++j) {
        m.x = fmaxf(m.x, v[j].x); m.y = fmaxf(m.y, v[j].y);
        m.z = fmaxf(m.z, v[j].z); m.w = fmaxf(m.w, v[j].w);
    }
    ((float4*)xm)[i4] = m;   // normal store: xm re-read by kernel B
}

// ---- Kernel B: early-exit conv from xm ----
__global__ __launch_bounds__(256, 2) void conv_kernel(const float* __restrict__ xm,
                                                      const float2* __restrict__ gent,
                                                      float* __restrict__ out) {
    __shared__ float xmt[LH][LW];
    __shared__ float2 ent[OCH * 26];
    int tid = threadIdx.x;
    int bid = blockIdx.x;
    int swz = (bid & 7) * (NWGB >> 3) + (bid >> 3);  // XCD-chunked, bijective
    int b   = swz >> 7;
    int t2  = swz & 127;
    int ty  = t2 >> 3;
    int tx  = t2 & 7;

    const float NI = -INFINITY;

    for (int i = tid; i < OCH * 26; i += 256) ent[i] = gent[i];

    // halo stage: 20 rows x 10 float4 from xm (L2/LLC-resident, 3.2KB/block)
    if (tid < 200) {
        int pr = tid / 10;
        int pc = tid % 10;
        int c4 = tx * 8 - 1 + pc;
        int rw = ty * TH - 2 + pr;
        bool valid = (c4 >= 0) && (c4 < WW / 4) && (rw >= 0) && (rw < HH);
        int c4c = c4 < 0 ? 0 : (c4 > WW / 4 - 1 ? WW / 4 - 1 : c4);
        int rwc = rw < 0 ? 0 : (rw > HH - 1 ? HH - 1 : rw);
        float4 m = *((const float4*)xm + (size_t)b * (HWSZ / 4)
                     + (size_t)rwc * (WW / 4) + c4c);
        if (!valid) { m.x = NI; m.y = NI; m.z = NI; m.w = NI; }
        *(float2*)&xmt[pr][4 * pc]     = make_float2(m.x, m.y);
        *(float2*)&xmt[pr][4 * pc + 2] = make_float2(m.z, m.w);
    }
    __syncthreads();

    // sorted-tap early-exit scan
    int xg = tid & 7;                                // 4 px
    int rg = (tid >> 3) & 7;                         // 2 rows
    int wv = __builtin_amdgcn_readfirstlane(tid >> 6);   // wave -> oc 8wv..8wv+7

    const char* r0p = (const char*)&xmt[2 * rg][4 * xg + 2];
    const char* r1p = (const char*)&xmt[2 * rg + 1][4 * xg + 2];

    size_t obase = (size_t)(b * OCH + wv * 8) * HWSZ
                 + (size_t)(ty * TH + 2 * rg) * WW + tx * TW + 4 * xg;

    for (int o = 0; o < 8; ++o) {
        const float2* E = &ent[(wv * 8 + o) * 26];
        float a00 = NI, a01 = NI, a02 = NI, a03 = NI;
        float a10 = NI, a11 = NI, a12 = NI, a13 = NI;

        for (int i = 0; i < 25; ++i) {
            float2 e  = E[i];                        // uniform -> LDS broadcast
            float  kn = E[i + 1].x;
            float  kv = e.x;
            int    off = __float_as_int(e.y);
            const float* p0 = (const float*)(r0p + off);
            const float* p1 = (const float*)(r1p + off);
            a00 = fmaxf(a00, fminf(p0[0], kv));
            a01 = fmaxf(a01, fminf(p0[1], kv));
            a02 = fmaxf(a02, fminf(p0[2], kv));
            a03 = fmaxf(a03, fminf(p0[3], kv));
            a10 = fmaxf(a10, fminf(p1[0], kv));
            a11 = fmaxf(a11, fminf(p1[1], kv));
            a12 = fmaxf(a12, fminf(p1[2], kv));
            a13 = fmaxf(a13, fminf(p1[3], kv));
            float mn = fminf(fminf(fminf(a00, a01), fminf(a02, a03)),
                             fminf(fminf(a10, a11), fminf(a12, a13)));
            if (__all(mn >= kn)) break;              // remaining cands <= kn <= a
        }

        float* op = out + obase + (size_t)o * HWSZ;
        floatx4 o0 = { a00, a01, a02, a03 };
        floatx4 o1 = { a10, a11, a12, a13 };
        __builtin_nontemporal_store(o0, (floatx4*)op);
        __builtin_nontemporal_store(o1, (floatx4*)(op + WW));
    }
}

extern "C" void kernel_launch(void* const* d_in, const int* in_sizes, int n_in,
                              void* d_out, int out_size, void* d_ws, size_t ws_size,
                              hipStream_t stream) {
    const float* x  = (const float*)d_in[0];
    const float* kk = (const float*)d_in[1];
    float* out      = (float*)d_out;
    float2* ent     = (float2*)d_ws;                       // 6656 B
    float*  xm      = (float*)((char*)d_ws + 8192);        // 4 MB

    sort_taps_kernel<<<1, OCH * 25, 0, stream>>>(kk, ent);
    chanmax_kernel<<<BATCH * HWSZ / 4 / 256, 256, 0, stream>>>(x, xm);
    conv_kernel<<<NWGB, 256, 0, stream>>>(xm, ent, out);
}

// Round 17
// 60.325 us; speedup vs baseline: 1.0613x; 1.0613x over previous
//
#include <hip/hip_runtime.h>
#include <math.h>

// out[b,oc,y,x] = max_t min(p_t, k_t), p = channel-max(32) of x, OOB=-inf.
// x (16,32,256,256) f32, k (32,5,5) f32, out (16,32,256,256) f32.
//
// r15 analysis: kernel runs at the ~6.25 TB/s vector-memory path ceiling ->
// only lever is moving fewer bytes. 32x16 tile had 1.56x halo read
// amplification; this round: 64x32 tile (1.195x) = 341 -> ~294 MB total.
// Sorted-tap early-exit scan reads taps from LDS (no reg window, no spill).

#define BATCH 16
#define CH    32
#define OCH   32
#define HH    256
#define WW    256
#define HWSZ  (HH * WW)
#define TW    64
#define TH    32
#define LH    36              // TH + 4
#define LW    76              // 72 data cols + 4 pad (16B-aligned rows)
#define NWG   (BATCH * (HH / TH) * (WW / TW))   // 512

typedef float floatx4 __attribute__((ext_vector_type(4)));

// ---- Kernel 0: rank taps (descending k), one block ----
__global__ void sort_taps_kernel(const float* __restrict__ kk, float2* __restrict__ ent) {
    int t = threadIdx.x;
    if (t >= OCH * 25) return;
    int oc = t / 25, i = t % 25;
    float ki = kk[oc * 25 + i];
    int rank = 0;
#pragma unroll
    for (int j = 0; j < 25; ++j) {
        float kj = kk[oc * 25 + j];
        rank += (kj > ki) || (kj == ki && j < i);
    }
    int dy = i / 5, dx = i % 5;
    int off = 4 * (dy * LW + dx);                 // byte offset in halo tile walk
    ent[oc * 26 + rank] = make_float2(ki, __int_as_float(off));
    if (i == 0) ent[oc * 26 + 25] = make_float2(-INFINITY, __int_as_float(0));
}

__global__ __launch_bounds__(512, 4) void fused_maxmin_kernel(const float* __restrict__ x,
                                                              const float2* __restrict__ gent,
                                                              float* __restrict__ out) {
    __shared__ float xmt[LH][LW];      // 64x32 core + halo, -inf at OOB
    __shared__ float2 ent[OCH * 26];
    int tid = threadIdx.x;
    int bid = blockIdx.x;
    int swz = (bid & 7) * (NWG >> 3) + (bid >> 3);   // XCD-chunked, bijective
    int b   = swz >> 5;                              // 32 tiles/batch
    int t2  = swz & 31;
    int ty  = t2 >> 2;                               // 0..7  (32-row bands)
    int tx  = t2 & 3;                                // 0..3  (64-col bands)

    const float NI = -INFINITY;

    for (int i = tid; i < OCH * 26; i += 512) ent[i] = gent[i];

    // ---- Phase 1: channel max of 36 rows x 18 float4 granules (648) ----
    for (int g = tid; g < 18 * LH; g += 512) {
        int pr = g / 18;
        int pc = g % 18;
        int c4 = tx * 16 - 1 + pc;                   // global float4 col
        int rw = ty * TH - 2 + pr;                   // global row
        bool valid = (c4 >= 0) && (c4 < WW / 4) && (rw >= 0) && (rw < HH);
        int c4c = c4 < 0 ? 0 : (c4 > WW / 4 - 1 ? WW / 4 - 1 : c4);
        int rwc = rw < 0 ? 0 : (rw > HH - 1 ? HH - 1 : rw);
        const float4* src = (const float4*)x + (size_t)b * CH * (HWSZ / 4)
                          + (size_t)rwc * (WW / 4) + c4c;
        float4 m = src[0];
#pragma unroll
        for (int c = 1; c < CH; ++c) {
            float4 v = src[(size_t)c * (HWSZ / 4)];
            m.x = fmaxf(m.x, v.x);
            m.y = fmaxf(m.y, v.y);
            m.z = fmaxf(m.z, v.z);
            m.w = fmaxf(m.w, v.w);
        }
        if (!valid) { m.x = NI; m.y = NI; m.z = NI; m.w = NI; }
        *(float4*)&xmt[pr][4 * pc] = m;              // LW%4==0 -> 16B aligned
    }
    __syncthreads();

    // ---- Phase 2: sorted-tap early-exit scan, straight from LDS ----
    int xg = tid & 7;                                // 4-px column group
    int rg = (tid >> 3) & 7;                         // 2-row group
    int wv = __builtin_amdgcn_readfirstlane(tid >> 6);   // wave -> oc 4wv..4wv+3

#pragma unroll
    for (int px = 0; px < 2; ++px) {
#pragma unroll
        for (int py = 0; py < 2; ++py) {
            int Y0 = 16 * py + 2 * rg;               // core row in tile
            int X0 = 32 * px + 4 * xg;               // core col in tile
            const char* r0p = (const char*)&xmt[Y0][X0 + 2];
            const char* r1p = (const char*)&xmt[Y0 + 1][X0 + 2];
            size_t pbase = (size_t)(ty * TH + Y0) * WW + tx * TW + X0;

            for (int o = 0; o < 4; ++o) {
                int oc = wv * 4 + o;
                const float2* E = &ent[oc * 26];
                float a00 = NI, a01 = NI, a02 = NI, a03 = NI;
                float a10 = NI, a11 = NI, a12 = NI, a13 = NI;

                for (int i = 0; i < 25; ++i) {
                    float2 e  = E[i];                // uniform -> LDS broadcast
                    float  kn = E[i + 1].x;
                    float  kv = e.x;
                    int    off = __float_as_int(e.y);
                    const float* p0 = (const float*)(r0p + off);
                    const float* p1 = (const float*)(r1p + off);
                    a00 = fmaxf(a00, fminf(p0[0], kv));
                    a01 = fmaxf(a01, fminf(p0[1], kv));
                    a02 = fmaxf(a02, fminf(p0[2], kv));
                    a03 = fmaxf(a03, fminf(p0[3], kv));
                    a10 = fmaxf(a10, fminf(p1[0], kv));
                    a11 = fmaxf(a11, fminf(p1[1], kv));
                    a12 = fmaxf(a12, fminf(p1[2], kv));
                    a13 = fmaxf(a13, fminf(p1[3], kv));
                    float mn = fminf(fminf(fminf(a00, a01), fminf(a02, a03)),
                                     fminf(fminf(a10, a11), fminf(a12, a13)));
                    if (__all(mn >= kn)) break;      // remaining cands <= kn <= a
                }

                float* op = out + (size_t)(b * OCH + oc) * HWSZ + pbase;
                floatx4 o0 = { a00, a01, a02, a03 };
                floatx4 o1 = { a10, a11, a12, a13 };
                __builtin_nontemporal_store(o0, (floatx4*)op);
                __builtin_nontemporal_store(o1, (floatx4*)(op + WW));
            }
        }
    }
}

extern "C" void kernel_launch(void* const* d_in, const int* in_sizes, int n_in,
                              void* d_out, int out_size, void* d_ws, size_t ws_size,
                              hipStream_t stream) {
    const float* x  = (const float*)d_in[0];
    const float* kk = (const float*)d_in[1];
    float* out      = (float*)d_out;
    float2* ent     = (float2*)d_ws;   // 6656 B

    sort_taps_kernel<<<1, OCH * 25, 0, stream>>>(kk, ent);
    fused_maxmin_kernel<<<NWG, 512, 0, stream>>>(x, ent, out);
}